// Round 1
// baseline (1207.808 us; speedup 1.0000x reference)
//
#include <hip/hip_runtime.h>
#include <stdint.h>

// Integrator: y = cumsum(x, axis=-1) over (8,4,1048576) fp32.
// Single-pass decoupled-lookback scan (rocPRIM/CUB style):
//   - init kernel zeroes 8192 packed {flag,value} descriptors (ws is poisoned)
//   - scan kernel: load tile once (HBM), local+block scan, publish aggregate
//     (single 64-bit agent-scope atomic store: flag in hi32, fp32 bits in lo32),
//     wave-parallel lookback over up to 64 predecessors/window, publish
//     inclusive, add offset, write y.
// HBM traffic: 134 MB read + 134 MB write (minimal). One big dispatch instead
// of two; no L3 re-read of x.

constexpr int ROWS           = 32;        // B*C = 8*4
constexpr int T_LEN          = 1048576;
constexpr int THREADS        = 256;
constexpr int PER_THREAD     = 16;        // contiguous floats per thread
constexpr int TILE           = THREADS * PER_THREAD;   // 4096
constexpr int BLOCKS_PER_ROW = T_LEN / TILE;           // 256
constexpr int TOTAL_BLOCKS   = ROWS * BLOCKS_PER_ROW;  // 8192

constexpr uint64_t FLAG_AGG = 1ull << 32;  // value = tile aggregate
constexpr uint64_t FLAG_INC = 2ull << 32;  // value = inclusive prefix

// ---------------- init: zero descriptors (64 KB) ----------------
__global__ __launch_bounds__(256) void integ_init(uint64_t* __restrict__ desc) {
  desc[blockIdx.x * 256 + threadIdx.x] = 0ull;
}

// ---------------- single-pass scan ----------------
__global__ __launch_bounds__(THREADS) void integ_scan1(
    const float* __restrict__ x, float* __restrict__ y,
    uint64_t* __restrict__ desc) {
  const int blk  = blockIdx.x;
  const int row  = blk >> 8;                 // / BLOCKS_PER_ROW
  const int tb   = blk & (BLOCKS_PER_ROW - 1);
  const int t    = threadIdx.x;
  const int lane = t & 63;
  const int wid  = t >> 6;

  __shared__ float s_wscan[4];   // per-wave inclusive totals
  __shared__ float s_excl;       // exclusive tile prefix from lookback

  // 1) load tile: 16 contiguous floats per thread
  const size_t base = (size_t)blk * TILE + (size_t)t * PER_THREAD;
  const float4* p = (const float4*)(x + base);
  float v[PER_THREAD];
#pragma unroll
  for (int j = 0; j < PER_THREAD / 4; ++j) {
    float4 q = p[j];
    v[4 * j + 0] = q.x; v[4 * j + 1] = q.y; v[4 * j + 2] = q.z; v[4 * j + 3] = q.w;
  }

  // 2) thread-local inclusive scan
#pragma unroll
  for (int i = 1; i < PER_THREAD; ++i) v[i] += v[i - 1];
  const float tsum = v[PER_THREAD - 1];

  // 3) wave scan of per-thread sums
  float s = tsum;
#pragma unroll
  for (int d = 1; d < 64; d <<= 1) {
    float n = __shfl_up(s, d, 64);
    if (lane >= d) s += n;
  }
  if (lane == 63) s_wscan[wid] = s;
  __syncthreads();

  const float blockTotal = (s_wscan[0] + s_wscan[1]) + (s_wscan[2] + s_wscan[3]);

  // 4) publish aggregate ASAP (single atomic word: flag|bits, agent scope)
  if (t == 0 && tb > 0) {
    uint64_t d = FLAG_AGG | (uint64_t)__float_as_uint(blockTotal);
    __hip_atomic_store(&desc[blk], d, __ATOMIC_RELEASE, __HIP_MEMORY_SCOPE_AGENT);
  }

  // 5) wave 0: decoupled lookback, 64 predecessors per window
  if (wid == 0) {
    float excl = 0.f;
    const int rowBase = row << 8;
    int idx = tb - 1 - lane;                 // this lane's predecessor (in-row)
    for (;;) {
      uint32_t flag; float val;
      if (idx >= 0) {
        uint64_t d;
        for (;;) {
          d = __hip_atomic_load(&desc[rowBase + idx], __ATOMIC_ACQUIRE,
                                __HIP_MEMORY_SCOPE_AGENT);
          if ((d >> 32) != 0ull) break;
          __builtin_amdgcn_s_sleep(1);       // light backoff while spinning
        }
        flag = (uint32_t)(d >> 32);
        val  = __uint_as_float((uint32_t)d);
      } else {                                // before row start: inclusive 0
        flag = 2u; val = 0.f;
      }
      const unsigned long long incMask = __ballot(flag == 2u);
      const int firstInc = incMask ? (__ffsll(incMask) - 1) : 64;
      // lanes closer than firstInc hold aggregates; lane firstInc holds the
      // inclusive prefix that closes the chain; farther lanes contribute 0.
      float contrib = (lane <= firstInc) ? val : 0.f;
#pragma unroll
      for (int o = 32; o > 0; o >>= 1) contrib += __shfl_xor(contrib, o, 64);
      excl += contrib;
      if (firstInc < 64) break;              // chain closed
      idx -= 64;                             // all aggregates: next window back
    }
    if (lane == 0) {
      uint64_t d = FLAG_INC | (uint64_t)__float_as_uint(excl + blockTotal);
      __hip_atomic_store(&desc[blk], d, __ATOMIC_RELEASE,
                         __HIP_MEMORY_SCOPE_AGENT);
      s_excl = excl;
    }
  }
  __syncthreads();

  // 6) add offsets and write
  float off = s_excl + (s - tsum);           // + exclusive prefix within wave
#pragma unroll
  for (int w = 0; w < 4; ++w) off += (w < wid) ? s_wscan[w] : 0.f;

#pragma unroll
  for (int i = 0; i < PER_THREAD; ++i) v[i] += off;

  float4* q = (float4*)(y + base);
#pragma unroll
  for (int j = 0; j < PER_THREAD / 4; ++j) {
    float4 o;
    o.x = v[4 * j + 0]; o.y = v[4 * j + 1];
    o.z = v[4 * j + 2]; o.w = v[4 * j + 3];
    q[j] = o;
  }
}

extern "C" void kernel_launch(void* const* d_in, const int* in_sizes, int n_in,
                              void* d_out, int out_size, void* d_ws, size_t ws_size,
                              hipStream_t stream) {
  const float* x = (const float*)d_in[0];
  float* y = (float*)d_out;
  uint64_t* desc = (uint64_t*)d_ws;   // TOTAL_BLOCKS u64 = 64 KB

  integ_init <<<TOTAL_BLOCKS / 256, 256, 0, stream>>>(desc);
  integ_scan1<<<TOTAL_BLOCKS,       THREADS, 0, stream>>>(x, y, desc);
}

// Round 2
// 372.141 us; speedup vs baseline: 3.2456x; 3.2456x over previous
//
#include <hip/hip_runtime.h>
#include <hip/hip_cooperative_groups.h>

// Integrator: y = cumsum(x, axis=-1) over (8,4,1048576) fp32.
// Single fused cooperative kernel (replaces the two-dispatch reduce-then-scan):
//   phase 1: each of 1024 blocks sums its 32768-float chunk -> part[1024]
//            (x read once from HBM, coalesced float4)
//   grid.sync()
//   phase 2: block sums its <=31 in-row predecessor chunk sums (L2-hot),
//            then scans its chunk tile-by-tile (x re-read hits Infinity Cache),
//            writes y. Carry propagates across the 8 tiles in-registers.
// One dispatch, one launch gap removed, 8x fewer blocks than round 0.
// HBM traffic: ~134 MB read + ~134 MB write (second x read is L3-resident).

namespace cg = cooperative_groups;

constexpr int ROWS           = 32;        // B*C = 8*4
constexpr int T_LEN          = 1048576;
constexpr int THREADS        = 256;
constexpr int BLOCKS_PER_ROW = 32;
constexpr int TOTAL_BLOCKS   = ROWS * BLOCKS_PER_ROW;   // 1024 (4 blocks/CU max)
constexpr int CHUNK          = T_LEN / BLOCKS_PER_ROW;  // 32768 floats
constexpr int PER_THREAD     = 16;
constexpr int TILE           = THREADS * PER_THREAD;    // 4096
constexpr int TILES_PER_CHUNK = CHUNK / TILE;           // 8

__global__ __launch_bounds__(THREADS, 4) void integ_fused(
    const float* __restrict__ x, float* __restrict__ y,
    float* __restrict__ part) {
  const int blk  = blockIdx.x;
  const int row  = blk >> 5;                // / BLOCKS_PER_ROW
  const int cb   = blk & 31;
  const int t    = threadIdx.x;
  const int lane = t & 63;
  const int wid  = t >> 6;

  const size_t cbase = (size_t)blk * CHUNK;

  __shared__ float s_red[4];

  // ---------------- phase 1: chunk sum ----------------
  {
    const float4* p = (const float4*)(x + cbase);
    float s0 = 0.f, s1 = 0.f, s2 = 0.f, s3 = 0.f;
#pragma unroll 2
    for (int j = 0; j < CHUNK / 4 / THREADS; j += 4) {  // 32 float4 / thread
      float4 a = p[(j + 0) * THREADS + t];
      float4 b = p[(j + 1) * THREADS + t];
      float4 c = p[(j + 2) * THREADS + t];
      float4 d = p[(j + 3) * THREADS + t];
      s0 += (a.x + a.y) + (a.z + a.w);
      s1 += (b.x + b.y) + (b.z + b.w);
      s2 += (c.x + c.y) + (c.z + c.w);
      s3 += (d.x + d.y) + (d.z + d.w);
    }
    float s = (s0 + s1) + (s2 + s3);
#pragma unroll
    for (int d = 32; d > 0; d >>= 1) s += __shfl_down(s, d, 64);
    if (lane == 0) s_red[wid] = s;
    __syncthreads();
    if (t == 0) part[blk] = (s_red[0] + s_red[1]) + (s_red[2] + s_red[3]);
  }

  cg::this_grid().sync();

  // ---------------- phase 2: offset + scan + write ----------------
  __shared__ float s_wscan[4];

  // predecessor chunk sums: <=31 values, every wave computes redundantly
  // (identical order -> bit-identical -> carry uniform across block)
  float ps = (lane < cb) ? part[(row << 5) + lane] : 0.f;
#pragma unroll
  for (int o = 32; o > 0; o >>= 1) ps += __shfl_xor(ps, o, 64);
  float carry = ps;

  for (int k = 0; k < TILES_PER_CHUNK; ++k) {
    const size_t base = cbase + (size_t)k * TILE + (size_t)t * PER_THREAD;
    const float4* p = (const float4*)(x + base);
    float v[PER_THREAD];
#pragma unroll
    for (int j = 0; j < PER_THREAD / 4; ++j) {
      float4 q = p[j];
      v[4 * j + 0] = q.x; v[4 * j + 1] = q.y;
      v[4 * j + 2] = q.z; v[4 * j + 3] = q.w;
    }

    // thread-local inclusive scan
#pragma unroll
    for (int i = 1; i < PER_THREAD; ++i) v[i] += v[i - 1];
    const float tsum = v[PER_THREAD - 1];

    // wave scan of per-thread sums
    float s = tsum;
#pragma unroll
    for (int d = 1; d < 64; d <<= 1) {
      float n = __shfl_up(s, d, 64);
      if (lane >= d) s += n;
    }
    if (lane == 63) s_wscan[wid] = s;
    __syncthreads();

    float off = carry + (s - tsum);           // + exclusive prefix within wave
#pragma unroll
    for (int w = 0; w < 4; ++w) off += (w < wid) ? s_wscan[w] : 0.f;
    const float blockTotal =
        (s_wscan[0] + s_wscan[1]) + (s_wscan[2] + s_wscan[3]);

#pragma unroll
    for (int i = 0; i < PER_THREAD; ++i) v[i] += off;

    float4* q = (float4*)(y + base);
#pragma unroll
    for (int j = 0; j < PER_THREAD / 4; ++j) {
      float4 o;
      o.x = v[4 * j + 0]; o.y = v[4 * j + 1];
      o.z = v[4 * j + 2]; o.w = v[4 * j + 3];
      q[j] = o;
    }

    carry += blockTotal;
    __syncthreads();                           // protect s_wscan reuse
  }
}

extern "C" void kernel_launch(void* const* d_in, const int* in_sizes, int n_in,
                              void* d_out, int out_size, void* d_ws, size_t ws_size,
                              hipStream_t stream) {
  const float* x = (const float*)d_in[0];
  float* y = (float*)d_out;
  float* part = (float*)d_ws;   // TOTAL_BLOCKS floats = 4 KB

  void* args[] = {(void*)&x, (void*)&y, (void*)&part};
  hipLaunchCooperativeKernel((const void*)integ_fused, dim3(TOTAL_BLOCKS),
                             dim3(THREADS), args, 0, stream);
}

// Round 3
// 258.133 us; speedup vs baseline: 4.6790x; 1.4417x over previous
//
#include <hip/hip_runtime.h>

// Integrator: y = cumsum(x, axis=-1) over (8,4,1048576) fp32.
// Two-dispatch reduce-then-scan (kernel boundary = the only cheap global
// barrier on MI355X: rounds 1-2 showed in-kernel cross-block sync costs
// 100+ us via the 8-XCD coherence fabric).
//   A: per-tile sums, 4096 blocks x 8192 floats (x read once, HBM-bound)
//   B: redundant per-wave reduce of <=127 predecessor tile sums (part[] is
//      16 KB, L2-hot), 32-elem/thread local scan, wave+block scan, write y
//      (x re-read is Infinity-Cache-resident: round-2 FETCH proved it).
// HBM floor: 134 MB read + 134 MB write.

constexpr int ROWS           = 32;        // B*C = 8*4
constexpr int T_LEN          = 1048576;
constexpr int THREADS        = 256;
constexpr int PER_THREAD     = 32;        // contiguous floats per thread
constexpr int TILE           = THREADS * PER_THREAD;   // 8192
constexpr int BLOCKS_PER_ROW = T_LEN / TILE;           // 128
constexpr int TOTAL_BLOCKS   = ROWS * BLOCKS_PER_ROW;  // 4096

// ---------------- A: per-tile sums ----------------
__global__ __launch_bounds__(THREADS) void integ_reduce(
    const float* __restrict__ x, float* __restrict__ part) {
  const int blk = blockIdx.x;
  const size_t base = (size_t)blk * TILE;
  const float4* p = (const float4*)(x + base);
  const int t = threadIdx.x;
  const int lane = t & 63;
  const int wid  = t >> 6;

  float s0 = 0.f, s1 = 0.f, s2 = 0.f, s3 = 0.f;
#pragma unroll
  for (int j = 0; j < TILE / 4 / THREADS; j += 4) {   // 8 float4 / thread
    float4 a = p[(j + 0) * THREADS + t];
    float4 b = p[(j + 1) * THREADS + t];
    float4 c = p[(j + 2) * THREADS + t];
    float4 d = p[(j + 3) * THREADS + t];
    s0 += (a.x + a.y) + (a.z + a.w);
    s1 += (b.x + b.y) + (b.z + b.w);
    s2 += (c.x + c.y) + (c.z + c.w);
    s3 += (d.x + d.y) + (d.z + d.w);
  }
  float s = (s0 + s1) + (s2 + s3);
#pragma unroll
  for (int d = 32; d > 0; d >>= 1) s += __shfl_down(s, d, 64);

  __shared__ float wsum[4];
  if (lane == 0) wsum[wid] = s;
  __syncthreads();
  if (t == 0) part[blk] = (wsum[0] + wsum[1]) + (wsum[2] + wsum[3]);
}

// ---------------- B: offset + local scan + write ----------------
__global__ __launch_bounds__(THREADS) void integ_scan(
    const float* __restrict__ x, float* __restrict__ y,
    const float* __restrict__ part) {
  const int blk = blockIdx.x;
  const int row = blk >> 7;                // / BLOCKS_PER_ROW
  const int tb  = blk & (BLOCKS_PER_ROW - 1);
  const int t = threadIdx.x;
  const int lane = t & 63;
  const int wid  = t >> 6;

  // 1) predecessor tile sums: each wave reduces all <=127 redundantly
  //    (identical order in every wave -> bit-identical carry, no LDS/barrier)
  const int rowBase = row << 7;
  float ps = 0.f;
  if (lane < tb)      ps += part[rowBase + lane];
  if (64 + lane < tb) ps += part[rowBase + 64 + lane];
#pragma unroll
  for (int o = 32; o > 0; o >>= 1) ps += __shfl_xor(ps, o, 64);
  const float carry = ps;

  // 2) load tile: 32 contiguous floats per thread (L3-resident after A)
  const size_t base = (size_t)blk * TILE + (size_t)t * PER_THREAD;
  const float4* p = (const float4*)(x + base);
  float v[PER_THREAD];
#pragma unroll
  for (int j = 0; j < PER_THREAD / 4; ++j) {
    float4 q = p[j];
    v[4 * j + 0] = q.x; v[4 * j + 1] = q.y;
    v[4 * j + 2] = q.z; v[4 * j + 3] = q.w;
  }

  // 3) thread-local inclusive scan
#pragma unroll
  for (int i = 1; i < PER_THREAD; ++i) v[i] += v[i - 1];
  const float tsum = v[PER_THREAD - 1];

  // 4) wave scan of per-thread sums
  float s = tsum;
#pragma unroll
  for (int d = 1; d < 64; d <<= 1) {
    float n = __shfl_up(s, d, 64);
    if (lane >= d) s += n;
  }
  __shared__ float s_wscan[4];
  if (lane == 63) s_wscan[wid] = s;
  __syncthreads();

  float off = carry + (s - tsum);          // + exclusive prefix within wave
#pragma unroll
  for (int w = 0; w < 4; ++w) off += (w < wid) ? s_wscan[w] : 0.f;

#pragma unroll
  for (int i = 0; i < PER_THREAD; ++i) v[i] += off;

  float4* q = (float4*)(y + base);
#pragma unroll
  for (int j = 0; j < PER_THREAD / 4; ++j) {
    float4 o;
    o.x = v[4 * j + 0]; o.y = v[4 * j + 1];
    o.z = v[4 * j + 2]; o.w = v[4 * j + 3];
    q[j] = o;
  }
}

extern "C" void kernel_launch(void* const* d_in, const int* in_sizes, int n_in,
                              void* d_out, int out_size, void* d_ws, size_t ws_size,
                              hipStream_t stream) {
  const float* x = (const float*)d_in[0];
  float* y = (float*)d_out;
  float* part = (float*)d_ws;   // TOTAL_BLOCKS floats = 16 KB

  integ_reduce<<<TOTAL_BLOCKS, THREADS, 0, stream>>>(x, part);
  integ_scan  <<<TOTAL_BLOCKS, THREADS, 0, stream>>>(x, y, part);
}